// Round 6
// baseline (380.608 us; speedup 1.0000x reference)
//
#include <hip/hip_runtime.h>

typedef __attribute__((ext_vector_type(4))) int i32x4;
typedef __attribute__((ext_vector_type(16))) int i32x16;
typedef unsigned long long ull;

#define D_IN  4096
#define D_OUT 4096
#define M_TOT 8192

// ==== fused quant + fragment-pack ===========================================
// Packed layout (unchanged, R4/R5-verified):
//   piece (mt, kt, hi, l31) at mt*131072 + kt*1024 + hi*512 + l31*16
//   holds q(row 32mt+l31, k = 32kt+16hi .. +16)
// Producer: block = 8 rows, 256 threads, 4 waves; wave w owns rows 2w, 2w+1.
// Whole row -> 64 float4 regs (coalesced), wave-local reduce (no syncthreads),
// quantize in-register, scatter into a 32KB LDS image (XOR-swizzled -> 2-way,
// free), one barrier, fully-coalesced store-out (128B full-line runs).
// 32KB LDS -> 5 blocks/CU: load/reduce/store phases of different blocks overlap.
__global__ __launch_bounds__(256, 4)
void quant_pack_kernel(const float* __restrict__ x, const float* __restrict__ W,
                       char* __restrict__ XP, char* __restrict__ WP,
                       float* __restrict__ sx, float* __restrict__ sn) {
  __shared__ __align__(16) char img[32768];   // [piece p<256][rl<8][16B], rl XOR-swizzled
  const int bid  = blockIdx.x;
  const int t    = threadIdx.x;
  const int lane = t & 63;
  const int wave = t >> 6;

  const bool isX = bid < (M_TOT / 8);
  const int  b2  = isX ? bid : bid - (M_TOT / 8);
  const float* src = isX ? x : W;
  char*  dst = isX ? XP : WP;
  float* sc  = isX ? sx : sn;

  // chunk c = j*64 + lane (float4) -> piece p = c>>2 = 16j + (lane>>2),
  // byte slot (lane&3)*4; img addr = p*128 + ((rl^(p&7))<<4) + s4, p&7 = g&7.
  const int g = lane >> 2, s4 = (lane & 3) << 2;

#pragma unroll
  for (int i = 0; i < 2; i++) {
    const int rl = wave * 2 + i;             // 0..7
    const int R  = b2 * 8 + rl;              // global row
    const float4* xr4 = (const float4*)(src + (size_t)R * D_IN);

    float4 v[16];
#pragma unroll
    for (int j = 0; j < 16; j++) v[j] = xr4[j * 64 + lane];   // coalesced 1KB/instr

    int* ip = (int*)(img + g * 128 + ((rl ^ (g & 7)) << 4) + s4);
    if (isX) {
      float mx = 0.f;
#pragma unroll
      for (int j = 0; j < 16; j++)
        mx = fmaxf(mx, fmaxf(fmaxf(fabsf(v[j].x), fabsf(v[j].y)),
                             fmaxf(fabsf(v[j].z), fabsf(v[j].w))));
#pragma unroll
      for (int off = 32; off; off >>= 1) mx = fmaxf(mx, __shfl_xor(mx, off));
      if (lane == 0) sc[R] = mx * (1.0f / 127.0f);
      const float inv = 127.0f / mx;
#pragma unroll
      for (int j = 0; j < 16; j++) {
        int q0 = (int)rintf(v[j].x * inv) & 255;
        int q1 = (int)rintf(v[j].y * inv) & 255;
        int q2 = (int)rintf(v[j].z * inv) & 255;
        int q3 = (int)rintf(v[j].w * inv) & 255;
        ip[j * 512] = q0 | (q1 << 8) | (q2 << 16) | (q3 << 24);   // +2048B per j
      }
    } else {
      double ss = 0.0;
#pragma unroll
      for (int j = 0; j < 16; j++)
        ss += (double)v[j].x * v[j].x + (double)v[j].y * v[j].y +
              (double)v[j].z * v[j].z + (double)v[j].w * v[j].w;
#pragma unroll
      for (int off = 32; off; off >>= 1) ss += __shfl_xor(ss, off);
      const float nrm = (float)sqrt(ss);
      if (lane == 0) sc[R] = nrm * (1.0f / 127.0f);
      const float den = nrm + 1e-8f;
#pragma unroll
      for (int j = 0; j < 16; j++) {
        float e[4] = {v[j].x, v[j].y, v[j].z, v[j].w};
        int q[4];
#pragma unroll
        for (int c = 0; c < 4; c++) {
          float wn = e[c] / den;
          wn = fminf(1.0f, fmaxf(-1.0f, wn));
          q[c] = (int)rintf(wn * 127.0f) & 255;
        }
        ip[j * 512] = q[0] | (q[1] << 8) | (q[2] << 16) | (q[3] << 24);
      }
    }
  }

  __syncthreads();

  // store-out: 2048 chunks of 16B; chunk c -> piece p=c>>3, row rl=c&7.
  // Global: contiguous 128B runs at stride 512 = full lines.
  const int mt = b2 >> 2;
  const int r5 = (b2 & 3) * 8;               // row offset within the 32-row group
  char* gbase = dst + (size_t)mt * 131072 + r5 * 16;
#pragma unroll
  for (int i = 0; i < 8; i++) {
    const int c  = t + 256 * i;
    const int p  = c >> 3;
    const int rl = c & 7;
    int4 val = *(const int4*)(img + p * 128 + ((rl ^ (p & 7)) << 4));
    *(int4*)(gbase + p * 512 + rl * 16) = val;
  }
}

// ==== flat i8 GEMM: fragment-direct loads, no LDS, no barriers ===============
// 512 blocks x 4 waves; wave tile 128x128 (block 256x256); BK=64.
// 3-deep fragment pipeline, vmcnt(32) steady. XCD map: XCD x owns A-panels
// [4x,4x+4) only -> concurrent L2 working set per XCD = 4 A + 8 B k-slices
// (192 KB); A slices L2-reused 8x, B slices 4x; fragment loads are L2 hits.
#define GLD(dst, p, off) \
  asm volatile("global_load_dwordx4 %0, %1, off offset:%2" : "=v"(dst) : "v"(p), "i"(off))

__device__ __forceinline__ void load16(ull (&pa)[4], ull (&pb)[4],
                                       i32x4 (&fa)[8], i32x4 (&fb)[8]) {
#pragma unroll
  for (int mi = 0; mi < 4; mi++) {
    GLD(fa[2 * mi],     pa[mi], 0);
    GLD(fa[2 * mi + 1], pa[mi], 1024);
    pa[mi] += 2048;
  }
#pragma unroll
  for (int ni = 0; ni < 4; ni++) {
    GLD(fb[2 * ni],     pb[ni], 0);
    GLD(fb[2 * ni + 1], pb[ni], 1024);
    pb[ni] += 2048;
  }
}

template<int VM>
__device__ __forceinline__ void mfma32(i32x4 (&fa)[8], i32x4 (&fb)[8],
                                       i32x16 (&acc)[4][4]) {
  asm volatile("s_waitcnt vmcnt(%[vm])"
               : "+v"(fa[0]), "+v"(fa[1]), "+v"(fa[2]), "+v"(fa[3]),
                 "+v"(fa[4]), "+v"(fa[5]), "+v"(fa[6]), "+v"(fa[7]),
                 "+v"(fb[0]), "+v"(fb[1]), "+v"(fb[2]), "+v"(fb[3]),
                 "+v"(fb[4]), "+v"(fb[5]), "+v"(fb[6]), "+v"(fb[7])
               : [vm] "i"(VM));
  __builtin_amdgcn_sched_barrier(0);
#pragma unroll
  for (int kk = 0; kk < 2; kk++)
#pragma unroll
    for (int mi = 0; mi < 4; mi++)
#pragma unroll
      for (int ni = 0; ni < 4; ni++)
        acc[mi][ni] = __builtin_amdgcn_mfma_i32_32x32x32_i8(
            fa[2 * mi + kk], fb[2 * ni + kk], acc[mi][ni], 0, 0, 0);
  __builtin_amdgcn_sched_barrier(0);
}

__global__ __launch_bounds__(256, 1)
void gemm_i8_kernel(const char* __restrict__ XP, const char* __restrict__ WP,
                    const float* __restrict__ sx, const float* __restrict__ sn,
                    const float* __restrict__ bias, float* __restrict__ C) {
  const int t = threadIdx.x;                 // 256 threads = 4 waves
  const int lane = t & 63;
  const int wave = t >> 6;
  const int wm = wave >> 1, wn = wave & 1;   // 2M x 2N, 128x128 per wave

  // XCD-aware map (bid%8 = XCD, round-robin dispatch): XCD x gets m-panels
  // [4x,4x+4) x all 16 n. Concurrent set on an XCD = 4m x 8n -> A window
  // L2-resident, each A k-slice reused by 8 blocks, each B slice by 4.
  const int bid = blockIdx.x;                // 512 = 32 m-blocks x 16 n-blocks
  const int xcd = bid & 7;
  const int j   = bid >> 3;                  // 0..63
  const int mblk = xcd * 4 + (j & 3);        // 0..31
  const int nblk = j >> 2;                   // 0..15
  const int m0 = mblk * 256, n0 = nblk * 256;

  // fragment base pointers: frag (mt, kt) at ((mt*128 + kt)*64 + lane)*16
  const int mt0 = (m0 >> 5) + wm * 4;
  const int nt0 = (n0 >> 5) + wn * 4;
  ull pa[4], pb[4];
#pragma unroll
  for (int mi = 0; mi < 4; mi++)
    pa[mi] = (ull)(XP + (size_t)(mt0 + mi) * 131072 + lane * 16);
#pragma unroll
  for (int ni = 0; ni < 4; ni++)
    pb[ni] = (ull)(WP + (size_t)(nt0 + ni) * 131072 + lane * 16);

  i32x16 acc[4][4];
#pragma unroll
  for (int i = 0; i < 4; i++)
#pragma unroll
    for (int jj = 0; jj < 4; jj++) acc[i][jj] = (i32x16)0;
  i32x4 fAa[8], fAb[8], fBa[8], fBb[8], fCa[8], fCb[8];   // 3-deep pipeline

  load16(pa, pb, fAa, fAb);                  // s0
  load16(pa, pb, fBa, fBb);                  // s1
#pragma unroll 1
  for (int it = 0; it < 20; ++it) {          // computes s0..s59, loads s2..s61
    load16(pa, pb, fCa, fCb);
    mfma32<32>(fAa, fAb, acc);
    load16(pa, pb, fAa, fAb);
    mfma32<32>(fBa, fBb, acc);
    load16(pa, pb, fBa, fBb);
    mfma32<32>(fCa, fCb, acc);
  }
  load16(pa, pb, fCa, fCb);                  // s62
  mfma32<32>(fAa, fAb, acc);                 // s60
  load16(pa, pb, fAa, fAb);                  // s63 (last; no OOB prefetch)
  mfma32<32>(fBa, fBb, acc);                 // s61
  mfma32<16>(fCa, fCb, acc);                 // s62
  mfma32<0>(fAa, fAb, acc);                  // s63

  // epilogue: D layout (32x32): col = lane&31, row = (r&3) + 8*(r>>2) + 4*(lane>>5)
  const int l31 = lane & 31;
  const int hi  = lane >> 5;
#pragma unroll
  for (int mi = 0; mi < 4; mi++) {
    const int rbase = m0 + wm * 128 + mi * 32 + hi * 4;
    float sxv[16];
#pragma unroll
    for (int r = 0; r < 16; r++) sxv[r] = sx[rbase + (r & 3) + 8 * (r >> 2)];
#pragma unroll
    for (int ni = 0; ni < 4; ni++) {
      const int col = n0 + wn * 128 + ni * 32 + l31;
      const float scn = sn[col];
      const float bv  = bias[col];
#pragma unroll
      for (int r = 0; r < 16; r++) {
        const int row = rbase + (r & 3) + 8 * (r >> 2);
        C[(size_t)row * D_OUT + col] =
            (float)acc[mi][ni][r] * (sxv[r] * scn) + bv;
      }
    }
  }
}

extern "C" void kernel_launch(void* const* d_in, const int* in_sizes, int n_in,
                              void* d_out, int out_size, void* d_ws, size_t ws_size,
                              hipStream_t stream) {
  const float* x    = (const float*)d_in[0];   // [4,2048,4096]
  const float* W    = (const float*)d_in[1];   // [4096,4096]
  const float* bias = (const float*)d_in[2];   // [4096]
  float* out = (float*)d_out;                  // [4,2048,4096]

  char* ws = (char*)d_ws;
  char*  xp = ws;                                             // 33.5 MB packed i8
  char*  wp = ws + (size_t)M_TOT * D_IN;                      // 16.8 MB packed i8
  float* sx = (float*)(wp + (size_t)D_OUT * D_IN);
  float* sn = sx + M_TOT;

  quant_pack_kernel<<<(M_TOT + D_OUT) / 8, 256, 0, stream>>>(x, W, xp, wp, sx, sn);
  gemm_i8_kernel<<<512, 256, 0, stream>>>(xp, wp, sx, sn, bias, out);
}